// Round 1
// baseline (62.393 us; speedup 1.0000x reference)
//
#include <hip/hip_runtime.h>
#include <math.h>

// Problem constants (from reference)
#define BATCH 2048
#define IN    512
#define OUT   512
#define NG    8
#define KTOT  1024   // concatenated K: [S | silu] x [Cw | w_b]

// GEMM tiling
#define BM 64
#define BN 64
#define BK 32
#define LDP 68   // padded LDS row (68*4=272B, multiple of 16B -> aligned float4 reads)

// ---------------------------------------------------------------------------
// prep_x: A'[b][i]     = sum_n exp(-(x[b,i]-g_n)^2)
//         A'[b][512+i] = silu(x[b,i])
// ---------------------------------------------------------------------------
__global__ __launch_bounds__(256) void prep_x_kernel(const float* __restrict__ x,
                                                     const float* __restrict__ grid,
                                                     float* __restrict__ A) {
    int idx = blockIdx.x * 256 + threadIdx.x;   // 0 .. BATCH*IN-1 (exact)
    float g[NG];
#pragma unroll
    for (int n = 0; n < NG; ++n) g[n] = grid[n];
    float xv = x[idx];
    float s = 0.f;
#pragma unroll
    for (int n = 0; n < NG; ++n) { float d = xv - g[n]; s += __expf(-d * d); }
    float silu = xv / (1.f + __expf(-xv));
    int b = idx >> 9;     // / IN
    int i = idx & 511;    // % IN
    A[b * KTOT + i]        = s;
    A[b * KTOT + 512 + i]  = silu;
}

// ---------------------------------------------------------------------------
// prep_b: B'[o][i]     = (sum_a c[a,o,i]) * w_s[o,i]
//         B'[o][512+i] = w_b[o,i]
// ---------------------------------------------------------------------------
__global__ __launch_bounds__(256) void prep_b_kernel(const float* __restrict__ c,
                                                     const float* __restrict__ w_b,
                                                     const float* __restrict__ w_s,
                                                     float* __restrict__ Bm) {
    int idx = blockIdx.x * 256 + threadIdx.x;   // 0 .. OUT*IN-1 (exact)
    float acc = 0.f;
#pragma unroll
    for (int a = 0; a < NG; ++a) acc += c[a * (OUT * IN) + idx];
    float cw = acc * w_s[idx];
    int o = idx >> 9;
    int i = idx & 511;
    Bm[o * KTOT + i]       = cw;
    Bm[o * KTOT + 512 + i] = w_b[idx];
}

// ---------------------------------------------------------------------------
// Tiled f32 GEMM: out[M=2048][N=512] = A'[M][K] * B'[N][K]^T  (NT layout)
// 64x64 block tile, BK=32, 256 threads, 4x4 per-thread micro-tile.
// ---------------------------------------------------------------------------
__global__ __launch_bounds__(256) void gemm_ws_kernel(const float* __restrict__ A,
                                                      const float* __restrict__ Bm,
                                                      float* __restrict__ outp) {
    __shared__ float As[BK][LDP];
    __shared__ float Bs[BK][LDP];

    int tid = threadIdx.x;
    int tx = tid & 15;    // N direction (o), 16 threads
    int ty = tid >> 4;    // M direction (b), 16 threads
    int m0 = blockIdx.y * BM;
    int n0 = blockIdx.x * BN;

    float acc[4][4] = {};

    for (int k0 = 0; k0 < KTOT; k0 += BK) {
        // Stage: 64 rows x 32 cols = 512 float4s per matrix; 2 per thread each.
#pragma unroll
        for (int t = 0; t < 2; ++t) {
            int f4 = tid + t * 256;
            int r  = f4 >> 3;     // row within tile (0..63)
            int c4 = f4 & 7;      // float4 index within the 32-wide K slice
            float4 av = *reinterpret_cast<const float4*>(&A[(size_t)(m0 + r) * KTOT + k0 + c4 * 4]);
            As[c4 * 4 + 0][r] = av.x;
            As[c4 * 4 + 1][r] = av.y;
            As[c4 * 4 + 2][r] = av.z;
            As[c4 * 4 + 3][r] = av.w;
            float4 bv = *reinterpret_cast<const float4*>(&Bm[(size_t)(n0 + r) * KTOT + k0 + c4 * 4]);
            Bs[c4 * 4 + 0][r] = bv.x;
            Bs[c4 * 4 + 1][r] = bv.y;
            Bs[c4 * 4 + 2][r] = bv.z;
            Bs[c4 * 4 + 3][r] = bv.w;
        }
        __syncthreads();

#pragma unroll
        for (int kk = 0; kk < BK; ++kk) {
            float4 a = *reinterpret_cast<const float4*>(&As[kk][ty * 4]);
            float4 b = *reinterpret_cast<const float4*>(&Bs[kk][tx * 4]);
            float av[4] = {a.x, a.y, a.z, a.w};
            float bv[4] = {b.x, b.y, b.z, b.w};
#pragma unroll
            for (int i = 0; i < 4; ++i)
#pragma unroll
                for (int j = 0; j < 4; ++j) acc[i][j] += av[i] * bv[j];
        }
        __syncthreads();
    }

#pragma unroll
    for (int i = 0; i < 4; ++i) {
        float4 v = make_float4(acc[i][0], acc[i][1], acc[i][2], acc[i][3]);
        *reinterpret_cast<float4*>(&outp[(size_t)(m0 + ty * 4 + i) * OUT + n0 + tx * 4]) = v;
    }
}

// ---------------------------------------------------------------------------
// Fallback: fully fused GEMM (no workspace). Stages A/B tiles by recomputing
// S/silu and Csum*w_s on the fly. Correct but slower; only used if ws_size
// is too small for the two-phase path.
// ---------------------------------------------------------------------------
__global__ __launch_bounds__(256) void gemm_fused_kernel(const float* __restrict__ x,
                                                         const float* __restrict__ c,
                                                         const float* __restrict__ w_b,
                                                         const float* __restrict__ w_s,
                                                         const float* __restrict__ grid,
                                                         float* __restrict__ outp) {
    __shared__ float As[BK][LDP];
    __shared__ float Bs[BK][LDP];

    int tid = threadIdx.x;
    int tx = tid & 15;
    int ty = tid >> 4;
    int m0 = blockIdx.y * BM;
    int n0 = blockIdx.x * BN;

    float g[NG];
#pragma unroll
    for (int n = 0; n < NG; ++n) g[n] = grid[n];

    float acc[4][4] = {};

    for (int k0 = 0; k0 < KTOT; k0 += BK) {
        bool spline_half = (k0 < 512);   // uniform: k0 is a multiple of 32
#pragma unroll
        for (int t = 0; t < 2; ++t) {
            int f4 = tid + t * 256;
            int r  = f4 >> 3;
            int c4 = f4 & 7;
#pragma unroll
            for (int e = 0; e < 4; ++e) {
                int k = k0 + c4 * 4 + e;
                int ki = spline_half ? k : (k - 512);
                // A element (row m0+r, col k)
                float xv = x[(size_t)(m0 + r) * IN + ki];
                float va;
                if (spline_half) {
                    float s = 0.f;
#pragma unroll
                    for (int n = 0; n < NG; ++n) { float d = xv - g[n]; s += __expf(-d * d); }
                    va = s;
                } else {
                    va = xv / (1.f + __expf(-xv));
                }
                As[c4 * 4 + e][r] = va;
                // B element (row n0+r, col k)
                float vb;
                if (spline_half) {
                    float a2 = 0.f;
#pragma unroll
                    for (int a = 0; a < NG; ++a) a2 += c[(size_t)a * (OUT * IN) + (size_t)(n0 + r) * IN + ki];
                    vb = a2 * w_s[(size_t)(n0 + r) * IN + ki];
                } else {
                    vb = w_b[(size_t)(n0 + r) * IN + ki];
                }
                Bs[c4 * 4 + e][r] = vb;
            }
        }
        __syncthreads();

#pragma unroll
        for (int kk = 0; kk < BK; ++kk) {
            float4 a = *reinterpret_cast<const float4*>(&As[kk][ty * 4]);
            float4 b = *reinterpret_cast<const float4*>(&Bs[kk][tx * 4]);
            float av[4] = {a.x, a.y, a.z, a.w};
            float bv[4] = {b.x, b.y, b.z, b.w};
#pragma unroll
            for (int i = 0; i < 4; ++i)
#pragma unroll
                for (int j = 0; j < 4; ++j) acc[i][j] += av[i] * bv[j];
        }
        __syncthreads();
    }

#pragma unroll
    for (int i = 0; i < 4; ++i) {
        float4 v = make_float4(acc[i][0], acc[i][1], acc[i][2], acc[i][3]);
        *reinterpret_cast<float4*>(&outp[(size_t)(m0 + ty * 4 + i) * OUT + n0 + tx * 4]) = v;
    }
}

extern "C" void kernel_launch(void* const* d_in, const int* in_sizes, int n_in,
                              void* d_out, int out_size, void* d_ws, size_t ws_size,
                              hipStream_t stream) {
    (void)in_sizes; (void)n_in; (void)out_size;
    const float* x    = (const float*)d_in[0];
    const float* c    = (const float*)d_in[1];
    const float* w_b  = (const float*)d_in[2];
    const float* w_s  = (const float*)d_in[3];
    const float* grid = (const float*)d_in[4];
    float* outp = (float*)d_out;

    size_t needA = (size_t)BATCH * KTOT * sizeof(float);   // 8 MiB
    size_t needB = (size_t)OUT   * KTOT * sizeof(float);   // 2 MiB

    dim3 ggrid(OUT / BN, BATCH / BM);   // 8 x 32 = 256 blocks

    if (ws_size >= needA + needB) {
        float* A  = (float*)d_ws;
        float* Bm = A + (size_t)BATCH * KTOT;
        prep_x_kernel<<<(BATCH * IN) / 256, 256, 0, stream>>>(x, grid, A);
        prep_b_kernel<<<(OUT * IN) / 256, 256, 0, stream>>>(c, w_b, w_s, Bm);
        gemm_ws_kernel<<<ggrid, 256, 0, stream>>>(A, Bm, outp);
    } else {
        gemm_fused_kernel<<<ggrid, 256, 0, stream>>>(x, c, w_b, w_s, grid, outp);
    }
}

// Round 2
// 23.295 us; speedup vs baseline: 2.6783x; 2.6783x over previous
//
#include <hip/hip_runtime.h>

// Problem constants
#define BATCH 2048
#define IN    512
#define OUT   512
#define NG    8
#define KTOT  1024   // concatenated K: [S | silu] x [Cw | w_b]

// GEMM tiling
#define BM 64
#define BN 64
#define BK 64
#define PAD 88                 // shorts per LDS row: 176B = 44 dwords -> conflict-free, 16B-aligned
#define NIT (KTOT / BK)        // 16

typedef __attribute__((ext_vector_type(8))) short bf16x8;
typedef __attribute__((ext_vector_type(4))) float f32x4;

__device__ inline unsigned short f2bf(float f) {
    union { float f; unsigned int u; } v; v.f = f;
    unsigned int r = v.u + 0x7fffu + ((v.u >> 16) & 1u);
    return (unsigned short)(r >> 16);
}

// ---------------------------------------------------------------------------
// Fused prep: blocks [0,512) build A' (bf16), blocks [512,640) build B' (bf16)
//   A'[b][i]      = sum_n exp(-(x[b,i]-g_n)^2)      A'[b][512+i] = silu(x[b,i])
//   B'[o][i]      = (sum_a c[a,o,i]) * w_s[o,i]     B'[o][512+i] = w_b[o,i]
// ---------------------------------------------------------------------------
__global__ __launch_bounds__(256) void prep_kernel(const float* __restrict__ x,
                                                   const float* __restrict__ c,
                                                   const float* __restrict__ w_b,
                                                   const float* __restrict__ w_s,
                                                   const float* __restrict__ grid,
                                                   unsigned short* __restrict__ A,
                                                   unsigned short* __restrict__ B) {
    int blk = blockIdx.x;
    int tid = threadIdx.x;
    if (blk < 512) {
        int e = (blk * 256 + tid) * 8;       // element base in x (row-aligned: 8 | 512)
        float g[NG];
#pragma unroll
        for (int n = 0; n < NG; ++n) g[n] = grid[n];
        float4 x0 = *(const float4*)&x[e];
        float4 x1 = *(const float4*)&x[e + 4];
        float xv[8] = {x0.x, x0.y, x0.z, x0.w, x1.x, x1.y, x1.z, x1.w};
        unsigned short sv[8], lv[8];
#pragma unroll
        for (int j = 0; j < 8; ++j) {
            float s = 0.f;
#pragma unroll
            for (int n = 0; n < NG; ++n) { float d = xv[j] - g[n]; s += __expf(-d * d); }
            sv[j] = f2bf(s);
            lv[j] = f2bf(xv[j] / (1.f + __expf(-xv[j])));
        }
        int b = e >> 9, i = e & 511;
        *(int4*)&A[b * KTOT + i]       = *(int4*)sv;
        *(int4*)&A[b * KTOT + 512 + i] = *(int4*)lv;
    } else {
        int e = ((blk - 512) * 256 + tid) * 8;
        float acc[8] = {};
#pragma unroll
        for (int a = 0; a < NG; ++a) {
            float4 c0 = *(const float4*)&c[(size_t)a * (OUT * IN) + e];
            float4 c1 = *(const float4*)&c[(size_t)a * (OUT * IN) + e + 4];
            acc[0] += c0.x; acc[1] += c0.y; acc[2] += c0.z; acc[3] += c0.w;
            acc[4] += c1.x; acc[5] += c1.y; acc[6] += c1.z; acc[7] += c1.w;
        }
        float4 s0 = *(const float4*)&w_s[e];
        float4 s1 = *(const float4*)&w_s[e + 4];
        float sw[8] = {s0.x, s0.y, s0.z, s0.w, s1.x, s1.y, s1.z, s1.w};
        float4 b0 = *(const float4*)&w_b[e];
        float4 b1 = *(const float4*)&w_b[e + 4];
        float bw[8] = {b0.x, b0.y, b0.z, b0.w, b1.x, b1.y, b1.z, b1.w};
        unsigned short cv[8], bv[8];
#pragma unroll
        for (int j = 0; j < 8; ++j) { cv[j] = f2bf(acc[j] * sw[j]); bv[j] = f2bf(bw[j]); }
        int o = e >> 9, i = e & 511;
        *(int4*)&B[o * KTOT + i]       = *(int4*)cv;
        *(int4*)&B[o * KTOT + 512 + i] = *(int4*)bv;
    }
}

// ---------------------------------------------------------------------------
// bf16 MFMA GEMM: out[2048][512] = A'[2048][1024] * B'[512][1024]^T
// 64x64 tile, 4 waves (each a 32x32 quadrant, 2x2 frags of 16x16x32), BK=64,
// reg-staged prefetch of the next K-slice between the barriers.
// ---------------------------------------------------------------------------
__global__ __launch_bounds__(256) void gemm_kernel(const unsigned short* __restrict__ A,
                                                   const unsigned short* __restrict__ B,
                                                   float* __restrict__ outp) {
    __shared__ short As[BM * PAD];
    __shared__ short Bs[BN * PAD];

    int tid  = threadIdx.x;
    int lane = tid & 63;
    int w    = tid >> 6;
    int wm   = w >> 1, wn = w & 1;
    int lr   = lane & 15, lg = lane >> 4;
    int m0   = blockIdx.y * BM;
    int n0   = blockIdx.x * BN;

    // staging map: 256 threads x 2 chunks/matrix; chunk = 16B = 8 bf16
    int srow = tid >> 3;   // 0..31 (t=1 adds 32)
    int sc8  = tid & 7;    // which 8-wide chunk of the 64-wide K slice

    const int4* Ag0 = (const int4*)&A[(size_t)(m0 + srow)      * KTOT + sc8 * 8];
    const int4* Ag1 = (const int4*)&A[(size_t)(m0 + srow + 32) * KTOT + sc8 * 8];
    const int4* Bg0 = (const int4*)&B[(size_t)(n0 + srow)      * KTOT + sc8 * 8];
    const int4* Bg1 = (const int4*)&B[(size_t)(n0 + srow + 32) * KTOT + sc8 * 8];
    // per K-iter advance: BK shorts = 8 int4s

    int wo0 = srow * PAD + sc8 * 8;
    int wo1 = (srow + 32) * PAD + sc8 * 8;

    f32x4 acc00 = {0.f, 0.f, 0.f, 0.f};
    f32x4 acc01 = {0.f, 0.f, 0.f, 0.f};
    f32x4 acc10 = {0.f, 0.f, 0.f, 0.f};
    f32x4 acc11 = {0.f, 0.f, 0.f, 0.f};

    int4 ca0 = Ag0[0], ca1 = Ag1[0], cb0 = Bg0[0], cb1 = Bg1[0];

#pragma unroll
    for (int it = 0; it < NIT; ++it) {
        *(int4*)&As[wo0] = ca0;
        *(int4*)&As[wo1] = ca1;
        *(int4*)&Bs[wo0] = cb0;
        *(int4*)&Bs[wo1] = cb1;
        __syncthreads();
        if (it + 1 < NIT) {   // prefetch next K-slice while MFMAs run
            ca0 = Ag0[(it + 1) * 8]; ca1 = Ag1[(it + 1) * 8];
            cb0 = Bg0[(it + 1) * 8]; cb1 = Bg1[(it + 1) * 8];
        }
#pragma unroll
        for (int ks = 0; ks < 2; ++ks) {
            bf16x8 a0 = *(const bf16x8*)&As[(wm * 32 + lr)      * PAD + ks * 32 + lg * 8];
            bf16x8 a1 = *(const bf16x8*)&As[(wm * 32 + 16 + lr) * PAD + ks * 32 + lg * 8];
            bf16x8 b0 = *(const bf16x8*)&Bs[(wn * 32 + lr)      * PAD + ks * 32 + lg * 8];
            bf16x8 b1 = *(const bf16x8*)&Bs[(wn * 32 + 16 + lr) * PAD + ks * 32 + lg * 8];
            acc00 = __builtin_amdgcn_mfma_f32_16x16x32_bf16(a0, b0, acc00, 0, 0, 0);
            acc01 = __builtin_amdgcn_mfma_f32_16x16x32_bf16(a0, b1, acc01, 0, 0, 0);
            acc10 = __builtin_amdgcn_mfma_f32_16x16x32_bf16(a1, b0, acc10, 0, 0, 0);
            acc11 = __builtin_amdgcn_mfma_f32_16x16x32_bf16(a1, b1, acc11, 0, 0, 0);
        }
        __syncthreads();
    }

    // C/D layout: col = lane&15, row = (lane>>4)*4 + reg   [measured m89/m91]
    int orow = m0 + wm * 32 + lg * 4;
    int ocol = n0 + wn * 32 + lr;
#pragma unroll
    for (int r = 0; r < 4; ++r) {
        outp[(size_t)(orow + r) * OUT + ocol]           = acc00[r];
        outp[(size_t)(orow + r) * OUT + ocol + 16]      = acc01[r];
        outp[(size_t)(orow + 16 + r) * OUT + ocol]      = acc10[r];
        outp[(size_t)(orow + 16 + r) * OUT + ocol + 16] = acc11[r];
    }
}

extern "C" void kernel_launch(void* const* d_in, const int* in_sizes, int n_in,
                              void* d_out, int out_size, void* d_ws, size_t ws_size,
                              hipStream_t stream) {
    (void)in_sizes; (void)n_in; (void)out_size; (void)ws_size;
    const float* x    = (const float*)d_in[0];
    const float* c    = (const float*)d_in[1];
    const float* w_b  = (const float*)d_in[2];
    const float* w_s  = (const float*)d_in[3];
    const float* grid = (const float*)d_in[4];
    float* outp = (float*)d_out;

    unsigned short* A = (unsigned short*)d_ws;             // 2048x1024 bf16 = 4 MiB
    unsigned short* B = A + (size_t)BATCH * KTOT;          // 512x1024 bf16 = 1 MiB

    prep_kernel<<<512 + 128, 256, 0, stream>>>(x, c, w_b, w_s, grid, A, B);
    gemm_kernel<<<dim3(OUT / BN, BATCH / BM), 256, 0, stream>>>(A, B, outp);
}

// Round 3
// 19.870 us; speedup vs baseline: 3.1401x; 1.1724x over previous
//
#include <hip/hip_runtime.h>

// Problem constants
#define BATCH 2048
#define IN    512
#define OUT   512
#define NG    8
#define KTOT  1024   // concatenated K: [S | silu] x [Cw | w_b]

// GEMM tiling
#define BM 64
#define BN 32
#define BK 64
#define PAD 88                 // shorts per LDS row: 176B, 16B-aligned, ~2-way banks (free)
#define NIT (KTOT / BK)        // 16

typedef __attribute__((ext_vector_type(8))) short bf16x8;
typedef __attribute__((ext_vector_type(4))) float f32x4;

__device__ inline unsigned short f2bf(float f) {
    union { float f; unsigned int u; } v; v.f = f;
    unsigned int r = v.u + 0x7fffu + ((v.u >> 16) & 1u);
    return (unsigned short)(r >> 16);
}

// ---------------------------------------------------------------------------
// Fused prep: blocks [0,512) build A' (bf16), blocks [512,640) build B' (bf16)
//   A'[b][i]      = sum_n exp(-(x[b,i]-g_n)^2)      A'[b][512+i] = silu(x[b,i])
//   B'[o][i]      = (sum_a c[a,o,i]) * w_s[o,i]     B'[o][512+i] = w_b[o,i]
// ---------------------------------------------------------------------------
__global__ __launch_bounds__(256) void prep_kernel(const float* __restrict__ x,
                                                   const float* __restrict__ c,
                                                   const float* __restrict__ w_b,
                                                   const float* __restrict__ w_s,
                                                   const float* __restrict__ grid,
                                                   unsigned short* __restrict__ A,
                                                   unsigned short* __restrict__ B) {
    int blk = blockIdx.x;
    int tid = threadIdx.x;
    if (blk < 512) {
        int e = (blk * 256 + tid) * 8;       // element base in x (row-aligned: 8 | 512)
        float g[NG];
#pragma unroll
        for (int n = 0; n < NG; ++n) g[n] = grid[n];
        float4 x0 = *(const float4*)&x[e];
        float4 x1 = *(const float4*)&x[e + 4];
        float xv[8] = {x0.x, x0.y, x0.z, x0.w, x1.x, x1.y, x1.z, x1.w};
        unsigned short sv[8], lv[8];
#pragma unroll
        for (int j = 0; j < 8; ++j) {
            float s = 0.f;
#pragma unroll
            for (int n = 0; n < NG; ++n) { float d = xv[j] - g[n]; s += __expf(-d * d); }
            sv[j] = f2bf(s);
            lv[j] = f2bf(xv[j] / (1.f + __expf(-xv[j])));
        }
        int b = e >> 9, i = e & 511;
        *(int4*)&A[b * KTOT + i]       = *(int4*)sv;
        *(int4*)&A[b * KTOT + 512 + i] = *(int4*)lv;
    } else {
        int e = ((blk - 512) * 256 + tid) * 8;
        float acc[8] = {};
#pragma unroll
        for (int a = 0; a < NG; ++a) {
            float4 c0 = *(const float4*)&c[(size_t)a * (OUT * IN) + e];
            float4 c1 = *(const float4*)&c[(size_t)a * (OUT * IN) + e + 4];
            acc[0] += c0.x; acc[1] += c0.y; acc[2] += c0.z; acc[3] += c0.w;
            acc[4] += c1.x; acc[5] += c1.y; acc[6] += c1.z; acc[7] += c1.w;
        }
        float4 s0 = *(const float4*)&w_s[e];
        float4 s1 = *(const float4*)&w_s[e + 4];
        float sw[8] = {s0.x, s0.y, s0.z, s0.w, s1.x, s1.y, s1.z, s1.w};
        float4 b0 = *(const float4*)&w_b[e];
        float4 b1 = *(const float4*)&w_b[e + 4];
        float bw[8] = {b0.x, b0.y, b0.z, b0.w, b1.x, b1.y, b1.z, b1.w};
        unsigned short cv[8], bv[8];
#pragma unroll
        for (int j = 0; j < 8; ++j) { cv[j] = f2bf(acc[j] * sw[j]); bv[j] = f2bf(bw[j]); }
        int o = e >> 9, i = e & 511;
        *(int4*)&B[o * KTOT + i]       = *(int4*)cv;
        *(int4*)&B[o * KTOT + 512 + i] = *(int4*)bv;
    }
}

// ---------------------------------------------------------------------------
// bf16 MFMA GEMM: out[2048][512] = A'[2048][1024] * B'[512][1024]^T
// 64x32 tile, 4 waves (each a 32x16 sub-tile: 2 M-frags x 1 N-frag of
// 16x16x32), BK=64, double-buffered LDS (1 barrier/iter), 2-deep reg prefetch.
// Grid = 512 blocks -> 2 blocks/CU -> 2 waves/SIMD.
// ---------------------------------------------------------------------------
__global__ __launch_bounds__(256) void gemm_kernel(const unsigned short* __restrict__ A,
                                                   const unsigned short* __restrict__ B,
                                                   float* __restrict__ outp) {
    __shared__ short As[2][BM * PAD];
    __shared__ short Bs[2][BN * PAD];

    int tid  = threadIdx.x;
    int lane = tid & 63;
    int w    = tid >> 6;
    int wm   = w >> 1, wn = w & 1;     // 2x2 wave grid over 64x32 tile
    int lr   = lane & 15, lg = lane >> 4;
    int m0   = blockIdx.y * BM;
    int n0   = blockIdx.x * BN;

    // staging map: chunk = 16B = 8 bf16. A: 64 rows x 8 chunks = 512 int4
    // (2/thread); B: 32 rows x 8 chunks = 256 int4 (1/thread).
    int srow = tid >> 3;   // 0..31
    int sc8  = tid & 7;

    const int4* Ag0 = (const int4*)&A[(size_t)(m0 + srow)      * KTOT + sc8 * 8];
    const int4* Ag1 = (const int4*)&A[(size_t)(m0 + srow + 32) * KTOT + sc8 * 8];
    const int4* Bg  = (const int4*)&B[(size_t)(n0 + srow)      * KTOT + sc8 * 8];
    // per K-iter advance: BK shorts = 8 int4s

    int woA0 = srow * PAD + sc8 * 8;
    int woA1 = (srow + 32) * PAD + sc8 * 8;
    int woB  = srow * PAD + sc8 * 8;

    f32x4 acc0 = {0.f, 0.f, 0.f, 0.f};
    f32x4 acc1 = {0.f, 0.f, 0.f, 0.f};

    // prologue: stage it=0 into buf0, prefetch it=1 into regs
    int4 ca0 = Ag0[0], ca1 = Ag1[0], cb = Bg[0];
    *(int4*)&As[0][woA0] = ca0;
    *(int4*)&As[0][woA1] = ca1;
    *(int4*)&Bs[0][woB]  = cb;
    ca0 = Ag0[8]; ca1 = Ag1[8]; cb = Bg[8];
    __syncthreads();

#pragma unroll
    for (int it = 0; it < NIT; ++it) {
        int cur = it & 1;
        if (it + 1 < NIT) {
            // write next tile (ordered vs prior readers by last iter's barrier)
            *(int4*)&As[cur ^ 1][woA0] = ca0;
            *(int4*)&As[cur ^ 1][woA1] = ca1;
            *(int4*)&Bs[cur ^ 1][woB]  = cb;
            if (it + 2 < NIT) {
                ca0 = Ag0[(it + 2) * 8]; ca1 = Ag1[(it + 2) * 8]; cb = Bg[(it + 2) * 8];
            }
        }
#pragma unroll
        for (int ks = 0; ks < 2; ++ks) {
            bf16x8 a0 = *(const bf16x8*)&As[cur][(wm * 32 + lr)      * PAD + ks * 32 + lg * 8];
            bf16x8 a1 = *(const bf16x8*)&As[cur][(wm * 32 + 16 + lr) * PAD + ks * 32 + lg * 8];
            bf16x8 b  = *(const bf16x8*)&Bs[cur][(wn * 16 + lr)      * PAD + ks * 32 + lg * 8];
            acc0 = __builtin_amdgcn_mfma_f32_16x16x32_bf16(a0, b, acc0, 0, 0, 0);
            acc1 = __builtin_amdgcn_mfma_f32_16x16x32_bf16(a1, b, acc1, 0, 0, 0);
        }
        __syncthreads();
    }

    // C/D layout: col = lane&15, row = (lane>>4)*4 + reg   [measured m89/m91]
    int orow = m0 + wm * 32 + lg * 4;
    int ocol = n0 + wn * 16 + lr;
#pragma unroll
    for (int r = 0; r < 4; ++r) {
        outp[(size_t)(orow + r) * OUT + ocol]      = acc0[r];
        outp[(size_t)(orow + 16 + r) * OUT + ocol] = acc1[r];
    }
}

extern "C" void kernel_launch(void* const* d_in, const int* in_sizes, int n_in,
                              void* d_out, int out_size, void* d_ws, size_t ws_size,
                              hipStream_t stream) {
    (void)in_sizes; (void)n_in; (void)out_size; (void)ws_size;
    const float* x    = (const float*)d_in[0];
    const float* c    = (const float*)d_in[1];
    const float* w_b  = (const float*)d_in[2];
    const float* w_s  = (const float*)d_in[3];
    const float* grid = (const float*)d_in[4];
    float* outp = (float*)d_out;

    unsigned short* A = (unsigned short*)d_ws;             // 2048x1024 bf16 = 4 MiB
    unsigned short* B = A + (size_t)BATCH * KTOT;          // 512x1024 bf16 = 1 MiB

    prep_kernel<<<512 + 128, 256, 0, stream>>>(x, c, w_b, w_s, grid, A, B);
    gemm_kernel<<<dim3(OUT / BN, BATCH / BM), 256, 0, stream>>>(A, B, outp);
}

// Round 4
// 17.731 us; speedup vs baseline: 3.5187x; 1.1206x over previous
//
#include <hip/hip_runtime.h>

// Problem constants
#define BATCH 2048
#define IN    512
#define OUT   512
#define NG    8
#define KTOT  1024   // concatenated K: [S | silu] x [Cw | w_b]

// GEMM tiling
#define BM 64
#define BN 64
#define BK 64
#define PAD 88                 // shorts per LDS row: 176B, 16B-aligned, <=2-way banks (free)
#define NIT (KTOT / BK)        // 16

typedef __attribute__((ext_vector_type(8))) short bf16x8;
typedef __attribute__((ext_vector_type(4))) float f32x4;

__device__ inline unsigned short f2bf(float f) {
    union { float f; unsigned int u; } v; v.f = f;
    unsigned int r = v.u + 0x7fffu + ((v.u >> 16) & 1u);
    return (unsigned short)(r >> 16);
}

// ---------------------------------------------------------------------------
// Fused prep: blocks [0,512) build A' (bf16), blocks [512,640) build B' (bf16)
//   A'[b][i]      = sum_n exp(-(x[b,i]-g_n)^2)      A'[b][512+i] = silu(x[b,i])
//   B'[o][i]      = (sum_a c[a,o,i]) * w_s[o,i]     B'[o][512+i] = w_b[o,i]
// Spline sum via uniform-grid factorization (3 exp instead of 9 per element):
//   u = x-g0, q = exp(2*D*u), S = exp(-u^2) * sum_n exp(-D^2 n^2) q^n (Horner)
// ---------------------------------------------------------------------------
__global__ __launch_bounds__(256) void prep_kernel(const float* __restrict__ x,
                                                   const float* __restrict__ c,
                                                   const float* __restrict__ w_b,
                                                   const float* __restrict__ w_s,
                                                   const float* __restrict__ grid,
                                                   unsigned short* __restrict__ A,
                                                   unsigned short* __restrict__ B) {
    int blk = blockIdx.x;
    int tid = threadIdx.x;
    if (blk < 512) {
        int e = (blk * 256 + tid) * 8;       // element base in x (row-aligned: 8 | 512)
        float g0 = grid[0];
        float dl = grid[1] - g0;             // uniform spacing (4/7)
        float d2 = dl * dl;
        float dn[NG];
#pragma unroll
        for (int n = 0; n < NG; ++n) dn[n] = __expf(-d2 * (float)(n * n));
        float4 x0 = *(const float4*)&x[e];
        float4 x1 = *(const float4*)&x[e + 4];
        float xv[8] = {x0.x, x0.y, x0.z, x0.w, x1.x, x1.y, x1.z, x1.w};
        unsigned short sv[8], lv[8];
#pragma unroll
        for (int j = 0; j < 8; ++j) {
            float u  = xv[j] - g0;
            float e1 = __expf(-u * u);
            float q  = __expf(2.f * dl * u);
            float p  = dn[NG - 1];
#pragma unroll
            for (int n = NG - 2; n >= 0; --n) p = p * q + dn[n];
            sv[j] = f2bf(e1 * p);
            lv[j] = f2bf(xv[j] / (1.f + __expf(-xv[j])));
        }
        int b = e >> 9, i = e & 511;
        *(int4*)&A[b * KTOT + i]       = *(int4*)sv;
        *(int4*)&A[b * KTOT + 512 + i] = *(int4*)lv;
    } else {
        int e = ((blk - 512) * 256 + tid) * 8;
        float acc[8] = {};
#pragma unroll
        for (int a = 0; a < NG; ++a) {
            float4 c0 = *(const float4*)&c[(size_t)a * (OUT * IN) + e];
            float4 c1 = *(const float4*)&c[(size_t)a * (OUT * IN) + e + 4];
            acc[0] += c0.x; acc[1] += c0.y; acc[2] += c0.z; acc[3] += c0.w;
            acc[4] += c1.x; acc[5] += c1.y; acc[6] += c1.z; acc[7] += c1.w;
        }
        float4 s0 = *(const float4*)&w_s[e];
        float4 s1 = *(const float4*)&w_s[e + 4];
        float sw[8] = {s0.x, s0.y, s0.z, s0.w, s1.x, s1.y, s1.z, s1.w};
        float4 b0 = *(const float4*)&w_b[e];
        float4 b1 = *(const float4*)&w_b[e + 4];
        float bw[8] = {b0.x, b0.y, b0.z, b0.w, b1.x, b1.y, b1.z, b1.w};
        unsigned short cv[8], bv[8];
#pragma unroll
        for (int j = 0; j < 8; ++j) { cv[j] = f2bf(acc[j] * sw[j]); bv[j] = f2bf(bw[j]); }
        int o = e >> 9, i = e & 511;
        *(int4*)&B[o * KTOT + i]       = *(int4*)cv;
        *(int4*)&B[o * KTOT + 512 + i] = *(int4*)bv;
    }
}

// ---------------------------------------------------------------------------
// bf16 MFMA GEMM: out[2048][512] = A'[2048][1024] * B'[512][1024]^T
// 64x64 tile, 512 threads = 8 waves (each 16x32: 1 A-frag x 2 B-frags of
// 16x16x32), BK=64, double-buffered LDS (1 barrier/iter), 2-deep reg prefetch.
// Grid = 256 blocks = 1 block/CU, 2 waves/SIMD.
// XCD mapping: bid%8 = m-strip group -> per-XCD working set (A strip 512KB +
// B 1MB) fits the 4MB per-XCD L2.
// ---------------------------------------------------------------------------
__global__ __launch_bounds__(512) void gemm_kernel(const unsigned short* __restrict__ A,
                                                   const unsigned short* __restrict__ B,
                                                   float* __restrict__ outp) {
    __shared__ short As[2][BM * PAD];
    __shared__ short Bs[2][BN * PAD];

    int tid  = threadIdx.x;
    int lane = tid & 63;
    int w    = tid >> 6;               // 0..7
    int wm   = w >> 1, wn = w & 1;     // 4x2 wave grid over 64x64 tile
    int lr   = lane & 15, lg = lane >> 4;

    // XCD-aware block id decode: mg = XCD-owned m-group (4 m-blocks),
    // rest = (sub-m, ncol)
    int bid  = blockIdx.x;
    int mg   = bid & 7;
    int rest = bid >> 3;
    int sub  = rest >> 3;              // 0..3
    int ncol = rest & 7;               // 0..7
    int m0   = (mg * 4 + sub) * BM;
    int n0   = ncol * BN;

    // staging map: chunk = 16B = 8 bf16; 64 rows x 8 chunks = 512 int4 per
    // matrix = 1/thread each for A and B.
    int srow = tid >> 3;   // 0..63
    int sc8  = tid & 7;

    const int4* Ag = (const int4*)&A[(size_t)(m0 + srow) * KTOT + sc8 * 8];
    const int4* Bg = (const int4*)&B[(size_t)(n0 + srow) * KTOT + sc8 * 8];
    // per K-iter advance: BK shorts = 8 int4s

    int wo = srow * PAD + sc8 * 8;

    f32x4 acc0 = {0.f, 0.f, 0.f, 0.f};
    f32x4 acc1 = {0.f, 0.f, 0.f, 0.f};

    // prologue: stage it=0 into buf0, prefetch it=1 into regs
    int4 ca = Ag[0], cb = Bg[0];
    *(int4*)&As[0][wo] = ca;
    *(int4*)&Bs[0][wo] = cb;
    ca = Ag[8]; cb = Bg[8];
    __syncthreads();

#pragma unroll
    for (int it = 0; it < NIT; ++it) {
        int cur = it & 1;
        if (it + 1 < NIT) {
            // write next tile (buf cur^1 was last read at it-1; barrier ordered)
            *(int4*)&As[cur ^ 1][wo] = ca;
            *(int4*)&Bs[cur ^ 1][wo] = cb;
            if (it + 2 < NIT) { ca = Ag[(it + 2) * 8]; cb = Bg[(it + 2) * 8]; }
        }
#pragma unroll
        for (int ks = 0; ks < 2; ++ks) {
            bf16x8 a  = *(const bf16x8*)&As[cur][(wm * 16 + lr)      * PAD + ks * 32 + lg * 8];
            bf16x8 b0 = *(const bf16x8*)&Bs[cur][(wn * 32 + lr)      * PAD + ks * 32 + lg * 8];
            bf16x8 b1 = *(const bf16x8*)&Bs[cur][(wn * 32 + 16 + lr) * PAD + ks * 32 + lg * 8];
            acc0 = __builtin_amdgcn_mfma_f32_16x16x32_bf16(a, b0, acc0, 0, 0, 0);
            acc1 = __builtin_amdgcn_mfma_f32_16x16x32_bf16(a, b1, acc1, 0, 0, 0);
        }
        __syncthreads();
    }

    // C/D layout: col = lane&15 (B-frag row), row = (lane>>4)*4 + reg (A side)
    int orow = m0 + wm * 16 + lg * 4;
    int ocol = n0 + wn * 32 + lr;
#pragma unroll
    for (int r = 0; r < 4; ++r) {
        outp[(size_t)(orow + r) * OUT + ocol]      = acc0[r];
        outp[(size_t)(orow + r) * OUT + ocol + 16] = acc1[r];
    }
}

extern "C" void kernel_launch(void* const* d_in, const int* in_sizes, int n_in,
                              void* d_out, int out_size, void* d_ws, size_t ws_size,
                              hipStream_t stream) {
    (void)in_sizes; (void)n_in; (void)out_size; (void)ws_size;
    const float* x    = (const float*)d_in[0];
    const float* c    = (const float*)d_in[1];
    const float* w_b  = (const float*)d_in[2];
    const float* w_s  = (const float*)d_in[3];
    const float* grid = (const float*)d_in[4];
    float* outp = (float*)d_out;

    unsigned short* A = (unsigned short*)d_ws;             // 2048x1024 bf16 = 4 MiB
    unsigned short* B = A + (size_t)BATCH * KTOT;          // 512x1024 bf16 = 1 MiB

    prep_kernel<<<512 + 128, 256, 0, stream>>>(x, c, w_b, w_s, grid, A, B);
    gemm_kernel<<<(BATCH / BM) * (OUT / BN), 512, 0, stream>>>(A, B, outp);
}